// Round 9
// baseline (108.953 us; speedup 1.0000x reference)
//
#include <hip/hip_runtime.h>
#include <math.h>

#define BATCH 4096
#define NODES 256
#define FDIM  128
#define HID   16

typedef __attribute__((ext_vector_type(8))) short short8;  // 8 bf16 (4 VGPRs)
typedef __attribute__((ext_vector_type(4))) float f32x4;   // MFMA C/D frag

// round-to-nearest-even bf16
__device__ __forceinline__ short bf_rn(float x) {
    const unsigned u = __float_as_uint(x);
    return (short)((u + 0x7FFF + ((u >> 16) & 1)) >> 16);
}
__device__ __forceinline__ float bf_back(short s) {
    return __uint_as_float(((unsigned)(unsigned short)s) << 16);
}
// x ~= hi + lo (RN both); with single-bf16 W: 2 MFMAs/tile, absmax ~4e-3
// (validated in R8 against the 1.93e-2 threshold).
__device__ __forceinline__ void split8(float4 v0, float4 v1,
                                       short8& hi, short8& lo) {
    float v[8] = {v0.x, v0.y, v0.z, v0.w, v1.x, v1.y, v1.z, v1.w};
    #pragma unroll
    for (int j = 0; j < 8; ++j) {
        const short h = bf_rn(v[j]);
        hi[j] = h;
        lo[j] = bf_rn(v[j] - bf_back(h));
    }
}

// ONE WAVE PER BATCH ELEMENT, ZERO BARRIERS.
// 1024 blocks x 256 threads; wave w owns b = blockIdx*4+w entirely:
// per-wave GEMM [256x128]x[128x16] as 16 M-tiles x 4 K-tiles of
// mfma_16x16x32_bf16 (x split hi/lo, W single RN-bf16 in 16 VGPRs).
// c0 = x0*At via wave-local reduce (2 shfl_xor over the g bits).
// e-vector in a wave-private LDS slice (in-wave lgkmcnt ordering, no
// __syncthreads anywhere); softmax = wave shuffle reduce; out = float4/lane.
// Rationale (R7/R8 post-mortems): barrier-coupled 4-wave blocks kept all
// co-resident waves phase-locked; independent waves let cold c0/weight
// phases of one wave hide under other waves' streaming loop.
// MFMA 16x16x32 layouts: A/B idx=lane&15, k=(lane>>4)*8+j; D col=lane&15,
// row=(lane>>4)*4+reg (numerically validated R6-R8).
__launch_bounds__(256)
__global__ void mta_kernel(const float* __restrict__ x,
                           const float* __restrict__ a1,
                           const float* __restrict__ a2,
                           const float* __restrict__ adj,
                           const int*  __restrict__ node_index,
                           const int*  __restrict__ type_index,
                           float* __restrict__ out) {
    const int tid  = threadIdx.x;
    const int lane = tid & 63;
    const int w    = tid >> 6;
    const int b    = blockIdx.x * 4 + w;   // this wave's batch element
    const int n    = lane & 15;            // output column (h) / A row idx
    const int g    = lane >> 4;            // k-group (0..3)

    __shared__ float es[4][NODES];         // wave-private 1KB slices

    const int t  = __builtin_amdgcn_readfirstlane(type_index[b]);
    const int ni = __builtin_amdgcn_readfirstlane(node_index[0]);

    const float* At  = a1 + (size_t)t * (2 * FDIM * HID); // top    [FDIM][HID]
    const float* Ab  = At + FDIM * HID;                   // bottom [FDIM][HID]
    const float* a2t = a2 + t * HID;
    const float* xb  = x + (size_t)b * NODES * FDIM;

    // ---- c0[n] = sum_f x0[f]*At[f][n]: lane (n,g) does f in [32g,32g+32),
    //      then butterfly over the two g bits (lane^16, lane^32).
    float c0 = 0.f;
    {
        const float* x0  = xb + (size_t)ni * FDIM + g * 32;
        const float* Atg = At + (g * 32) * HID + n;
        #pragma unroll
        for (int j4 = 0; j4 < 8; ++j4) {
            const float4 xv = *(const float4*)(x0 + j4 * 4);
            c0 = fmaf(xv.x, Atg[(j4 * 4 + 0) * HID], c0);
            c0 = fmaf(xv.y, Atg[(j4 * 4 + 1) * HID], c0);
            c0 = fmaf(xv.z, Atg[(j4 * 4 + 2) * HID], c0);
            c0 = fmaf(xv.w, Atg[(j4 * 4 + 3) * HID], c0);
        }
        c0 += __shfl_xor(c0, 16);
        c0 += __shfl_xor(c0, 32);
    }

    // ---- weight B-fragments (RN bf16): lane holds Ab[k][n], k=kt*32+g*8+j --
    short8 wfrag[4];
    #pragma unroll
    for (int kt = 0; kt < 4; ++kt) {
        #pragma unroll
        for (int j = 0; j < 8; ++j)
            wfrag[kt][j] = bf_rn(Ab[(kt * 32 + g * 8 + j) * HID + n]); // L2-hot
    }
    const float a2h = a2t[n];

    // ---- main: 16 M-tiles, acc = one f32x4 at a time, no barriers ----
    float* esw = es[w];
    #pragma unroll 1
    for (int mt = 0; mt < 16; ++mt) {
        float4 ra[4][2];
        #pragma unroll
        for (int kt = 0; kt < 4; ++kt) {     // 8 loads in flight
            const float* p = xb + (size_t)(mt * 16 + n) * FDIM
                           + kt * 32 + g * 8;
            ra[kt][0] = *(const float4*)p;
            ra[kt][1] = *(const float4*)(p + 4);
        }
        f32x4 acc = (f32x4){0.f, 0.f, 0.f, 0.f};
        #pragma unroll
        for (int kt = 0; kt < 4; ++kt) {
            short8 ahi, alo;
            split8(ra[kt][0], ra[kt][1], ahi, alo);
            acc = __builtin_amdgcn_mfma_f32_16x16x32_bf16(ahi, wfrag[kt], acc, 0, 0, 0);
            acc = __builtin_amdgcn_mfma_f32_16x16x32_bf16(alo, wfrag[kt], acc, 0, 0, 0);
        }
        // epilogue for these 16 rows: e = lrelu( sum_h lrelu(acc+c0)*a2 )
        #pragma unroll
        for (int r = 0; r < 4; ++r) {
            float v = acc[r] + c0;
            v = (v > 0.f) ? v : 0.01f * v;
            float s = v * a2h;
            s += __shfl_xor(s, 1);
            s += __shfl_xor(s, 2);
            s += __shfl_xor(s, 4);
            s += __shfl_xor(s, 8);           // sum over 16 h-lanes
            const float e = (s > 0.f) ? s : 0.01f * s;
            if (n == 0) esw[mt * 16 + g * 4 + r] = e;   // wave-private LDS
        }
    }

    // ---- wave-local masked softmax: lane owns rows 4*lane..4*lane+3 ----
    const float4 ev = *(const float4*)&esw[lane * 4];   // in-wave lgkmcnt
    const float4 mv = *(const float4*)&adj[lane * 4];
    const float NEG = -INFINITY;
    float e0 = (mv.x > 0.f) ? ev.x : NEG;
    float e1 = (mv.y > 0.f) ? ev.y : NEG;
    float e2 = (mv.z > 0.f) ? ev.z : NEG;
    float e3 = (mv.w > 0.f) ? ev.w : NEG;

    float mx = fmaxf(fmaxf(e0, e1), fmaxf(e2, e3));
    #pragma unroll
    for (int off = 32; off; off >>= 1) mx = fmaxf(mx, __shfl_xor(mx, off));

    const float p0 = (mv.x > 0.f) ? __expf(e0 - mx) : 0.f;
    const float p1 = (mv.y > 0.f) ? __expf(e1 - mx) : 0.f;
    const float p2 = (mv.z > 0.f) ? __expf(e2 - mx) : 0.f;
    const float p3 = (mv.w > 0.f) ? __expf(e3 - mx) : 0.f;

    float s = (p0 + p1) + (p2 + p3);
    #pragma unroll
    for (int off = 32; off; off >>= 1) s += __shfl_xor(s, off);
    const float rz = 1.f / s;

    float4 ov = {p0 * rz, p1 * rz, p2 * rz, p3 * rz};
    *(float4*)&out[(size_t)b * NODES + lane * 4] = ov;   // coalesced 1KB/wave
}

extern "C" void kernel_launch(void* const* d_in, const int* in_sizes, int n_in,
                              void* d_out, int out_size, void* d_ws, size_t ws_size,
                              hipStream_t stream) {
    const float* x   = (const float*)d_in[0];
    const float* a1  = (const float*)d_in[1];
    const float* a2  = (const float*)d_in[2];
    const float* adj = (const float*)d_in[3];
    const int*   ni  = (const int*)d_in[4];
    const int*   ti  = (const int*)d_in[5];
    float* out = (float*)d_out;

    mta_kernel<<<BATCH / 4, 256, 0, stream>>>(x, a1, a2, adj, ni, ti, out);
}

// Round 10
// 107.875 us; speedup vs baseline: 1.0100x; 1.0100x over previous
//
#include <hip/hip_runtime.h>
#include <math.h>

#define BATCH 4096
#define NODES 256
#define FDIM  128
#define HID   16

typedef __attribute__((ext_vector_type(8))) short short8;  // 8 bf16
typedef __attribute__((ext_vector_type(4))) float f32x4;   // MFMA C/D frag

__device__ __forceinline__ short bf_rn(float x) {
    const unsigned u = __float_as_uint(x);
    return (short)((u + 0x7FFF + ((u >> 16) & 1)) >> 16);
}
__device__ __forceinline__ float bf_back(short s) {
    return __uint_as_float(((unsigned)(unsigned short)s) << 16);
}
// x ~= hi + lo (RN both); W single RN-bf16 -> 2 MFMAs/tile, absmax ~4e-3
// (validated R8/R9 vs the 1.93e-2 threshold).
__device__ __forceinline__ void split8(float4 v0, float4 v1,
                                       short8& hi, short8& lo) {
    float v[8] = {v0.x, v0.y, v0.z, v0.w, v1.x, v1.y, v1.z, v1.w};
    #pragma unroll
    for (int j = 0; j < 8; ++j) {
        const short h = bf_rn(v[j]);
        hi[j] = h;
        lo[j] = bf_rn(v[j] - bf_back(h));
    }
}

__device__ __forceinline__ void gload_lds16(const float* g, void* l) {
    __builtin_amdgcn_global_load_lds(
        (const __attribute__((address_space(1))) void*)g,
        (__attribute__((address_space(3))) void*)l, 16, 0, 0);
}

// ONE WAVE PER BATCH ELEMENT, ZERO BARRIERS, STAGED CONTIGUOUS LOADS.
// R9 skeleton + the single change under test: x M-tiles (16 rows x 128 f =
// 8KB) staged via global_load_lds width-16 where EVERY instruction moves a
// contiguous 1KB (2 full rows, 16 lines fully consumed by one instruction)
// instead of direct per-lane fragment loads (32 half-lines per instruction).
// Wave-private double buffer, counted s_waitcnt vmcnt(8) (T4: never 0 in
// loop). Fragment reads: ds_read_b128 with XOR swizzle c16 ^= (row&7),
// pre-applied on the GLOBAL source (rule #21: linear LDS dest + inverse-swz
// source + swz read) -> 8 accesses/bank/instr = LDS floor rate.
// MFMA 16x16x32: A/B idx=lane&15, k=(lane>>4)*8+j; D col=lane&15,
// row=(lane>>4)*4+reg (numerically validated R6-R9).
__launch_bounds__(256)
__global__ void mta_kernel(const float* __restrict__ x,
                           const float* __restrict__ a1,
                           const float* __restrict__ a2,
                           const float* __restrict__ adj,
                           const int*  __restrict__ node_index,
                           const int*  __restrict__ type_index,
                           float* __restrict__ out) {
    const int tid  = threadIdx.x;
    const int lane = tid & 63;
    const int w    = tid >> 6;
    const int b    = blockIdx.x * 4 + w;   // this wave's batch element
    const int n    = lane & 15;            // h column / A row idx
    const int g    = lane >> 4;            // k-group (0..3)

    __shared__ __align__(16) float stg[4][2][16 * FDIM];  // 4 waves x 2 x 8KB
    __shared__ float es[4][NODES];                        // wave-private

    const int t  = __builtin_amdgcn_readfirstlane(type_index[b]);
    const int ni = __builtin_amdgcn_readfirstlane(node_index[0]);

    const float* At  = a1 + (size_t)t * (2 * FDIM * HID); // top    [FDIM][HID]
    const float* Ab  = At + FDIM * HID;                   // bottom [FDIM][HID]
    const float* a2t = a2 + t * HID;
    const float* xb  = x + (size_t)b * NODES * FDIM;

    // ---- c0[n] = sum_f x0[f]*At[f][n]: lane (n,g) covers f in [32g,32g+32),
    //      butterfly over the g bits.
    float c0 = 0.f;
    {
        const float* x0  = xb + (size_t)ni * FDIM + g * 32;
        const float* Atg = At + (g * 32) * HID + n;
        #pragma unroll
        for (int j4 = 0; j4 < 8; ++j4) {
            const float4 xv = *(const float4*)(x0 + j4 * 4);
            c0 = fmaf(xv.x, Atg[(j4 * 4 + 0) * HID], c0);
            c0 = fmaf(xv.y, Atg[(j4 * 4 + 1) * HID], c0);
            c0 = fmaf(xv.z, Atg[(j4 * 4 + 2) * HID], c0);
            c0 = fmaf(xv.w, Atg[(j4 * 4 + 3) * HID], c0);
        }
        c0 += __shfl_xor(c0, 16);
        c0 += __shfl_xor(c0, 32);
    }

    // ---- weight B-fragments (RN bf16): lane holds Ab[k][n], k=kt*32+g*8+j --
    short8 wfrag[4];
    #pragma unroll
    for (int kt = 0; kt < 4; ++kt) {
        #pragma unroll
        for (int j = 0; j < 8; ++j)
            wfrag[kt][j] = bf_rn(Ab[(kt * 32 + g * 8 + j) * HID + n]); // L2-hot
    }
    const float a2h = a2t[n];
    float* esw = es[w];

    // stage M-tile mt into wave-private buf p: instr i moves contiguous 1KB
    // (rows 2i,2i+1); source col16 pre-swizzled ^(row&7) within the row.
    auto stg_tile = [&](int mt, int p) {
        float* dst = &stg[w][p][0];
        const float* src = xb + (size_t)mt * 16 * FDIM;
        #pragma unroll
        for (int i = 0; i < 8; ++i) {
            const int s   = i * 64 + lane;
            const int row = s >> 5;
            const int c16 = s & 31;
            gload_lds16(src + row * FDIM + ((c16 ^ (row & 7)) << 2),
                        (char*)dst + i * 1024);
        }
    };

    // ---- main: 16 M-tiles, double-buffered, counted vmcnt, no barriers ----
    stg_tile(0, 0);
    #pragma unroll 1
    for (int mt = 0; mt < 16; ++mt) {
        const int p = mt & 1;
        if (mt + 1 < 16) {
            stg_tile(mt + 1, p ^ 1);                      // 8 loads in flight
            asm volatile("s_waitcnt vmcnt(8)" ::: "memory");  // tile mt ready
        } else {
            asm volatile("s_waitcnt vmcnt(0)" ::: "memory");
        }

        const char* srcb = (const char*)&stg[w][p][0];
        f32x4 acc = (f32x4){0.f, 0.f, 0.f, 0.f};
        #pragma unroll
        for (int kt = 0; kt < 4; ++kt) {
            const int ca = kt * 8 + g * 2;                // 16B-slot index
            const float4 v0 = *(const float4*)(srcb + n * 512 + ((ca ^ (n & 7)) << 4));
            const float4 v1 = *(const float4*)(srcb + n * 512 + (((ca + 1) ^ (n & 7)) << 4));
            short8 ahi, alo;
            split8(v0, v1, ahi, alo);
            acc = __builtin_amdgcn_mfma_f32_16x16x32_bf16(ahi, wfrag[kt], acc, 0, 0, 0);
            acc = __builtin_amdgcn_mfma_f32_16x16x32_bf16(alo, wfrag[kt], acc, 0, 0, 0);
        }

        // epilogue for these 16 rows: e = lrelu( sum_h lrelu(acc+c0)*a2 )
        #pragma unroll
        for (int r = 0; r < 4; ++r) {
            float v = acc[r] + c0;
            v = (v > 0.f) ? v : 0.01f * v;
            float s = v * a2h;
            s += __shfl_xor(s, 1);
            s += __shfl_xor(s, 2);
            s += __shfl_xor(s, 4);
            s += __shfl_xor(s, 8);           // sum over 16 h-lanes
            const float e = (s > 0.f) ? s : 0.01f * s;
            if (n == 0) esw[mt * 16 + g * 4 + r] = e;
        }
    }

    // ---- wave-local masked softmax: lane owns rows 4*lane..4*lane+3 ----
    const float4 ev = *(const float4*)&esw[lane * 4];   // in-wave lgkmcnt
    const float4 mv = *(const float4*)&adj[lane * 4];
    const float NEG = -INFINITY;
    float e0 = (mv.x > 0.f) ? ev.x : NEG;
    float e1 = (mv.y > 0.f) ? ev.y : NEG;
    float e2 = (mv.z > 0.f) ? ev.z : NEG;
    float e3 = (mv.w > 0.f) ? ev.w : NEG;

    float mx = fmaxf(fmaxf(e0, e1), fmaxf(e2, e3));
    #pragma unroll
    for (int off = 32; off; off >>= 1) mx = fmaxf(mx, __shfl_xor(mx, off));

    const float p0 = (mv.x > 0.f) ? __expf(e0 - mx) : 0.f;
    const float p1 = (mv.y > 0.f) ? __expf(e1 - mx) : 0.f;
    const float p2 = (mv.z > 0.f) ? __expf(e2 - mx) : 0.f;
    const float p3 = (mv.w > 0.f) ? __expf(e3 - mx) : 0.f;

    float s = (p0 + p1) + (p2 + p3);
    #pragma unroll
    for (int off = 32; off; off >>= 1) s += __shfl_xor(s, off);
    const float rz = 1.f / s;

    float4 ov = {p0 * rz, p1 * rz, p2 * rz, p3 * rz};
    *(float4*)&out[(size_t)b * NODES + lane * 4] = ov;   // coalesced 1KB/wave
}

extern "C" void kernel_launch(void* const* d_in, const int* in_sizes, int n_in,
                              void* d_out, int out_size, void* d_ws, size_t ws_size,
                              hipStream_t stream) {
    const float* x   = (const float*)d_in[0];
    const float* a1  = (const float*)d_in[1];
    const float* a2  = (const float*)d_in[2];
    const float* adj = (const float*)d_in[3];
    const int*   ni  = (const int*)d_in[4];
    const int*   ti  = (const int*)d_in[5];
    float* out = (float*)d_out;

    mta_kernel<<<BATCH / 4, 256, 0, stream>>>(x, a1, a2, adj, ni, ti, out);
}

// Round 11
// 101.599 us; speedup vs baseline: 1.0724x; 1.0618x over previous
//
#include <hip/hip_runtime.h>
#include <math.h>

#define BATCH 4096
#define NODES 256
#define FDIM  128
#define HID   16

typedef __attribute__((ext_vector_type(8))) short short8;  // 8 bf16 (4 VGPRs)
typedef __attribute__((ext_vector_type(4))) float f32x4;   // MFMA C/D frag

// bf16 split: x ~= hi + lo (truncation); 3 MFMAs (hi*hi+hi*lo+lo*hi) ~= fp32.
__device__ __forceinline__ short bf_trunc(float x) {
    return (short)(__float_as_uint(x) >> 16);
}
__device__ __forceinline__ float bf_back(short s) {
    return __uint_as_float(((unsigned)(unsigned short)s) << 16);
}
__device__ __forceinline__ void split8(float4 v0, float4 v1,
                                       short8& hi, short8& lo) {
    float v[8] = {v0.x, v0.y, v0.z, v0.w, v1.x, v1.y, v1.z, v1.w};
    #pragma unroll
    for (int j = 0; j < 8; ++j) {
        const short h = bf_trunc(v[j]);
        hi[j] = h;
        lo[j] = bf_trunc(v[j] - bf_back(h));
    }
}

// FINAL (= round-6 kernel, best of 5 structural variants at 101.5us):
// one block per batch element b; 4 waves; wave w owns rows 64w..64w+63 as
// 4 M-tiles of 16. Per-block GEMM [256x128]x[128x16] via mfma_16x16x32_bf16;
// weights in B-fragments (hi+lo bf16, 32 VGPRs, loaded once per block);
// x loaded straight global->VGPR in A-frag layout, split hi/lo, 3 MFMAs/tile.
// c0 (the concat-top term x0*At) computed cooperatively once per block.
//
// Roofline evidence (R6-R10): five independent structures — direct fragment
// loads (this), contiguous global_load_lds staging + counted vmcnt (R10),
// barrier-free 1-wave-per-b (R9), occupancy 2..6 waves/SIMD (R7/R8) — all
// land 101.5-109us. Sustained 512MB/101.5us = 5.1 TB/s unidirectional read;
// TLP in flight ~10x the BW*latency product; VALU/MFMA time ~4x under BW
// time. Conclusion: effective read-stream ceiling of the machine.
__launch_bounds__(256, 2)   // empirical: VGPR cap = 256/min_waves = 128
__global__ void mta_kernel(const float* __restrict__ x,
                           const float* __restrict__ a1,
                           const float* __restrict__ a2,
                           const float* __restrict__ adj,
                           const int*  __restrict__ node_index,
                           const int*  __restrict__ type_index,
                           float* __restrict__ out) {
    const int b    = blockIdx.x;
    const int tid  = threadIdx.x;
    const int lane = tid & 63;
    const int w    = tid >> 6;
    const int n    = lane & 15;   // output column (h) / A row idx
    const int g    = lane >> 4;   // k-group (0..3)

    __shared__ float es[NODES];
    __shared__ float part[16][17];
    __shared__ float c0s[HID];
    __shared__ float redm[4], reds[4];

    const int t  = __builtin_amdgcn_readfirstlane(type_index[b]);
    const int ni = __builtin_amdgcn_readfirstlane(node_index[0]);

    const float* At  = a1 + (size_t)t * (2 * FDIM * HID); // top    [FDIM][HID]
    const float* Ab  = At + FDIM * HID;                   // bottom [FDIM][HID]
    const float* a2t = a2 + t * HID;
    const float* xb  = x + (size_t)b * NODES * FDIM;

    // ---- c0[h] = sum_f x[b,ni,f] * At[f][h] (cooperative, fp32) ----
    {
        const float* x0 = xb + (size_t)ni * FDIM;
        const int f2 = tid >> 4;
        const int h  = tid & 15;
        float p = 0.f;
        #pragma unroll
        for (int j = 0; j < 8; ++j) {
            const int f = f2 * 8 + j;
            p = fmaf(x0[f], At[f * HID + h], p);
        }
        part[f2][h] = p;
    }
    __syncthreads();
    if (tid < 16) {
        float s = 0.f;
        #pragma unroll
        for (int gg = 0; gg < 16; ++gg) s += part[gg][tid];
        c0s[tid] = s;
    }
    __syncthreads();

    // ---- weight B-fragments: lane supplies Ab[k][n], k = kt*32 + g*8 + j ----
    short8 whi[4], wlo[4];
    #pragma unroll
    for (int kt = 0; kt < 4; ++kt) {
        float wv[8];
        #pragma unroll
        for (int j = 0; j < 8; ++j)
            wv[j] = Ab[(kt * 32 + g * 8 + j) * HID + n];   // L2-hot, 8KB shared
        float4 w0 = {wv[0], wv[1], wv[2], wv[3]};
        float4 w1 = {wv[4], wv[5], wv[6], wv[7]};
        split8(w0, w1, whi[kt], wlo[kt]);
    }

    // ---- main GEMM: 4 K-tiles x 4 M-tiles, A straight from global ----
    const int rowbase = w * 64;
    f32x4 acc[4];
    #pragma unroll
    for (int mt = 0; mt < 4; ++mt) acc[mt] = (f32x4){0.f, 0.f, 0.f, 0.f};

    #pragma unroll
    for (int kt = 0; kt < 4; ++kt) {
        float4 ra[4][2];
        #pragma unroll
        for (int mt = 0; mt < 4; ++mt) {
            const float* p = xb + (size_t)(rowbase + mt * 16 + n) * FDIM
                           + kt * 32 + g * 8;
            ra[mt][0] = *(const float4*)p;
            ra[mt][1] = *(const float4*)(p + 4);
        }
        #pragma unroll
        for (int mt = 0; mt < 4; ++mt) {
            short8 ahi, alo;
            split8(ra[mt][0], ra[mt][1], ahi, alo);
            acc[mt] = __builtin_amdgcn_mfma_f32_16x16x32_bf16(ahi, whi[kt], acc[mt], 0, 0, 0);
            acc[mt] = __builtin_amdgcn_mfma_f32_16x16x32_bf16(ahi, wlo[kt], acc[mt], 0, 0, 0);
            acc[mt] = __builtin_amdgcn_mfma_f32_16x16x32_bf16(alo, whi[kt], acc[mt], 0, 0, 0);
        }
    }

    // ---- epilogue: e[row] = lrelu( sum_h lrelu(acc+c0[h]) * a2[h] ) ----
    const float c0h = c0s[n];
    const float a2h = a2t[n];
    #pragma unroll
    for (int mt = 0; mt < 4; ++mt) {
        #pragma unroll
        for (int r = 0; r < 4; ++r) {
            float v = acc[mt][r] + c0h;
            v = (v > 0.f) ? v : 0.01f * v;
            float s = v * a2h;
            s += __shfl_xor(s, 1);
            s += __shfl_xor(s, 2);
            s += __shfl_xor(s, 4);
            s += __shfl_xor(s, 8);      // sum over 16 h-lanes
            float e = (s > 0.f) ? s : 0.01f * s;
            if (n == 0) es[rowbase + mt * 16 + g * 4 + r] = e;
        }
    }
    __syncthreads();

    // ---- masked softmax over 256 nodes ----
    const float ee  = es[tid];
    const float m   = adj[tid];
    float       val = (m > 0.f) ? ee : -INFINITY;

    float mx = val;
    #pragma unroll
    for (int off = 32; off; off >>= 1) mx = fmaxf(mx, __shfl_xor(mx, off));
    const int wid = tid >> 6;
    if ((tid & 63) == 0) redm[wid] = mx;
    __syncthreads();
    mx = fmaxf(fmaxf(redm[0], redm[1]), fmaxf(redm[2], redm[3]));

    float pr = (m > 0.f) ? __expf(ee - mx) : 0.f;
    float s = pr;
    #pragma unroll
    for (int off = 32; off; off >>= 1) s += __shfl_xor(s, off);
    if ((tid & 63) == 0) reds[wid] = s;
    __syncthreads();
    const float Z = reds[0] + reds[1] + reds[2] + reds[3];

    out[(size_t)b * NODES + tid] = pr / Z;
}

extern "C" void kernel_launch(void* const* d_in, const int* in_sizes, int n_in,
                              void* d_out, int out_size, void* d_ws, size_t ws_size,
                              hipStream_t stream) {
    const float* x   = (const float*)d_in[0];
    const float* a1  = (const float*)d_in[1];
    const float* a2  = (const float*)d_in[2];
    const float* adj = (const float*)d_in[3];
    const int*   ni  = (const int*)d_in[4];
    const int*   ti  = (const int*)d_in[5];
    float* out = (float*)d_out;

    mta_kernel<<<BATCH, NODES, 0, stream>>>(x, a1, a2, adj, ni, ti, out);
}